// Round 20
// baseline (175.115 us; speedup 1.0000x reference)
//
#include <hip/hip_runtime.h>

// ---------------------------------------------------------------------------
// NonLocalBlockND — bf16 MFMA pipeline, round 20 = round 19 (173.4 us) +
//  * Y relocated B_R1 -> B_F (exact 7,077,888-byte fit in the dead gap), so
//    XT (bf16 q-major x transpose) stays ALIVE through zcat.
//  * k_zcat residual read switched from f32 c-major x (28.3 MB, 64B segs)
//    to bf16 q-major XT (14.2 MB, u16x8 fully coalesced, each elem read
//    once). Epilogue: phase-1 tl[q][136c] = bf16(acc+wzb); phase-2 applies
//    (v + xt)*dww + dwb during coalesced read-back.
// Everything else identical to round 19.
// ---------------------------------------------------------------------------

typedef __attribute__((ext_vector_type(8))) short bf16x8;
typedef __attribute__((ext_vector_type(4))) float f32x4;
typedef unsigned short u16;
struct alignas(8) u16x4 { u16 x, y, z, w; };
struct alignas(16) u16x8 { u16 e[8]; };

constexpr int B_ = 4, C_ = 256, N_ = 2304, CI_ = 128;
constexpr long long NN_ = (long long)N_ * N_;

constexpr size_t B_WB = 0;
constexpr size_t B_WZ = 589824;
constexpr size_t B_PW = 786432;
constexpr size_t B_R1 = 2359296;
constexpr size_t B_R2 = 16515072;
constexpr size_t B_GP = 30670848;
constexpr size_t B_F  = 37748736;    // per-batch F (fallback) / Y (both paths)
constexpr size_t B_A  = 69599232;    // per-batch-layout A_bf
constexpr size_t B_FF = 44826624;                    // F (4,3,N,N) fp16
constexpr size_t B_AF = 172228608;                   // A_bf (4,N,N) bf16
constexpr size_t WS_FULL = 214695936;

__device__ __forceinline__ u16 f2bf(float f) {
  unsigned u = __float_as_uint(f);
  u += 0x7fff + ((u >> 16) & 1);
  return (u16)(u >> 16);
}
__device__ __forceinline__ float bf2f(u16 u) {
  return __uint_as_float((unsigned)u << 16);
}
__device__ __forceinline__ u16 f2h(float f) {
  _Float16 h = (_Float16)f;
  return __builtin_bit_cast(u16, h);
}
__device__ __forceinline__ float h2f(u16 u) {
  return (float)__builtin_bit_cast(_Float16, u);
}

__device__ __forceinline__ void gload16(const void* g, void* l) {
  __builtin_amdgcn_global_load_lds((const __attribute__((address_space(1))) void*)g,
                                   (__attribute__((address_space(3))) void*)l,
                                   16, 0, 0);
}

template<int N> __device__ __forceinline__ void vwait() {
  asm volatile("s_waitcnt vmcnt(%0)" :: "i"(N) : "memory");
}
__device__ __forceinline__ void barrier_() {
  asm volatile("" ::: "memory");
  __builtin_amdgcn_s_barrier();
  asm volatile("" ::: "memory");
}

// m204 bijective XCD-chunk swizzle (grid % 8 == 0 for all users).
__device__ __forceinline__ int xcd_swz() {
  const int nwg = (int)gridDim.x, orig = (int)blockIdx.x;
  const int q = nwg >> 3, r = nwg & 7;
  const int xcd = orig & 7, pos = orig >> 3;
  return (xcd < r ? xcd * (q + 1) : r * (q + 1) + (xcd - r) * q) + pos;
}

// ========== uniform 256-thread core: 128x128 tile, BK=32, depth-3 ring =======
__device__ __forceinline__ void stage32(const char* Ag, int ldaB,
                                        const char* Bg, int ldbB,
                                        char* As, char* Bs, int t) {
  #pragma unroll
  for (int c = 0; c < 2; ++c) {
    const int idx = (c * 256 + t) * 16;
    const int row = idx >> 6;
    const int gc = (idx & 63) ^ (((row >> 1) & 3) << 4);
    gload16(Ag + (size_t)row * ldaB + gc, As + idx);
    gload16(Bg + (size_t)row * ldbB + gc, Bs + idx);
  }
}

__device__ __forceinline__ void comp32(const char* As, const char* Bs,
                                       f32x4 (&acc)[4][4],
                                       int arow, int brow, int kb) {
  bf16x8 af[4], bfr[4];
  #pragma unroll
  for (int i = 0; i < 4; ++i) {
    af[i]  = *(const bf16x8*)(As + (arow + i * 16) * 64 + kb);
    bfr[i] = *(const bf16x8*)(Bs + (brow + i * 16) * 64 + kb);
  }
  __builtin_amdgcn_s_setprio(1);
  #pragma unroll
  for (int mf = 0; mf < 4; ++mf)
    #pragma unroll
    for (int nf = 0; nf < 4; ++nf)
      acc[mf][nf] = __builtin_amdgcn_mfma_f32_16x16x32_bf16(
          af[mf], bfr[nf], acc[mf][nf], 0, 0, 0);
  __builtin_amdgcn_s_setprio(0);
}

__device__ __forceinline__ void gemm256c(const char* Ab, int ldaB,
                                         const char* Bb, int ldbB,
                                         int kIters, f32x4 (&acc)[4][4],
                                         char* lds) {
  const int t = (int)threadIdx.x, l = t & 63, w = t >> 6;
  const int arow = (w >> 1) * 64 + (l & 15);
  const int brow = (w & 1) * 64 + (l & 15);
  const int kb = ((l >> 4) * 16) ^ ((((l & 15) >> 1) & 3) << 4);
  char* A0 = lds;          char* B0 = lds + 8192;
  char* A1 = lds + 16384;  char* B1 = lds + 24576;
  char* A2 = lds + 32768;  char* B2 = lds + 40960;
  stage32(Ab,      ldaB, Bb,      ldbB, A0, B0, t);
  stage32(Ab + 64, ldaB, Bb + 64, ldbB, A1, B1, t);
  for (int kt = 0; kt < kIters - 2; ++kt) {
    stage32(Ab + (size_t)(kt + 2) * 64, ldaB,
            Bb + (size_t)(kt + 2) * 64, ldbB, A2, B2, t);
    vwait<8>();
    barrier_();
    comp32(A0, B0, acc, arow, brow, kb);
    barrier_();
    char* ta = A0; A0 = A1; A1 = A2; A2 = ta;
    char* tb = B0; B0 = B1; B1 = B2; B2 = tb;
  }
  vwait<4>();
  barrier_();
  comp32(A0, B0, acc, arow, brow, kb);
  vwait<0>();
  barrier_();
  comp32(A1, B1, acc, arow, brow, kb);
}

#define EPI_SETUP \
  const int el = (int)threadIdx.x & 63, ew = (int)threadIdx.x >> 6; \
  const int rb = (ew >> 1) * 64 + ((el >> 4) << 2); \
  const int cb = (ew & 1) * 64 + (el & 15);

// ---------------- merged convert: x transpose (z<12) + weights (z==12) ------
struct CvtA { const float* s[13]; const float* x[3]; };
__global__ __launch_bounds__(256) void k_cvt(CvtA ca, u16* WB, u16* XT) {
  const int t = threadIdx.x;
  if (blockIdx.z == 12) {           // weight-convert slab: flat 1,179,648 f32
    const int bid = blockIdx.y * 36 + blockIdx.x;   // 0..143
    #pragma unroll
    for (int i = 0; i < 8; ++i) {
      const int flat = (i * 36864 + bid * 256 + t) * 4;
      int seg, base;
      if (flat < 294912)      { seg = flat >> 15;            base = seg << 15; }
      else if (flat < 393216) { seg = 9 + ((flat - 294912) >> 15);
                                base = 294912 + ((seg - 9) << 15); }
      else                    { seg = 12;                    base = 393216; }
      f32x4 v = *(const f32x4*)(ca.s[seg] + (flat - base));
      u16x4 o; o.x = f2bf(v[0]); o.y = f2bf(v[1]); o.z = f2bf(v[2]); o.w = f2bf(v[3]);
      *(u16x4*)(WB + flat) = o;
    }
    return;
  }
  __shared__ float tile[64][65];
  const int q0 = blockIdx.x * 64, c0 = blockIdx.y * 64;
  const int vb = blockIdx.z, v = vb >> 2, b = vb & 3;
  const float* src = ca.x[v] + ((size_t)b * C_ + c0) * N_ + q0;
  #pragma unroll
  for (int i = 0; i < 4; ++i) {
    int idx = t + i * 256;
    int r = idx >> 4, q4 = (idx & 15) * 4;
    f32x4 val = *(const f32x4*)(src + (size_t)r * N_ + q4);
    tile[r][q4 + 0] = val[0]; tile[r][q4 + 1] = val[1];
    tile[r][q4 + 2] = val[2]; tile[r][q4 + 3] = val[3];
  }
  __syncthreads();
  u16* dst = XT + ((size_t)vb * N_ + q0) * 256 + c0;
  const int q = t >> 2, cp = (t & 3) * 16;
  u16 tmp[16];
  #pragma unroll
  for (int jj = 0; jj < 16; ++jj) tmp[jj] = f2bf(tile[cp + jj][q]);
  #pragma unroll
  for (int s4 = 0; s4 < 4; ++s4) {
    u16x4 o; o.x = tmp[s4 * 4]; o.y = tmp[s4 * 4 + 1];
    o.z = tmp[s4 * 4 + 2]; o.w = tmp[s4 * 4 + 3];
    *(u16x4*)(dst + (size_t)q * 256 + cp + s4 * 4) = o;
  }
}

// ---------------- proj (256t, 1-D grid 648 XCD-swizzled, kIters=8) ----------
struct ProjA { const float* bias[9]; };
__global__ __launch_bounds__(256) void k_proj(const u16* WB, const u16* XT,
                                              u16* TH, u16* PH, u16* GP, ProjA pa) {
  __shared__ char lds[49152];
  const int lid = xcd_swz();
  const int col0 = (lid % 18) * 128;                 // q
  const int pz = lid / 18;
  const int p = pz >> 2, b = pz & 3;
  const int v = p / 3, pt = p % 3;
  const char* Ab = (const char*)(WB + (size_t)p * 32768);
  const char* Bb = (const char*)(XT + ((size_t)(v * 4 + b) * N_ + col0) * 256);
  f32x4 acc[4][4] = {};
  gemm256c(Ab, 512, Bb, 512, 8, acc, lds);
  EPI_SETUP;
  const int t = (int)threadIdx.x;
  const float* bias = pa.bias[p];
  u16* tl = (u16*)lds;
  __syncthreads();                   // K-loop LDS reads done; reuse tile
  if (pt == 0) {                     // GP natural (ci, m): tile [ci][136 m]
    #pragma unroll
    for (int mf = 0; mf < 4; ++mf) {
      const int row = rb + mf * 16;  // ci
      f32x4 bv = *(const f32x4*)(bias + row);
      #pragma unroll
      for (int nf = 0; nf < 4; ++nf)
        #pragma unroll
        for (int r = 0; r < 4; ++r)
          tl[(row + r) * 136 + cb + nf * 16] = f2bf(acc[mf][nf][r] + bv[r]);
    }
    __syncthreads();
    u16* dst = GP + (size_t)(v * 4 + b) * CI_ * N_;
    const int m8 = (t & 15) * 8;
    #pragma unroll
    for (int rr = 0; rr < 8; ++rr) {
      const int ci = (t >> 4) + rr * 16;
      *(u16x8*)(dst + (size_t)ci * N_ + col0 + m8) =
          *(const u16x8*)(tl + ci * 136 + m8);
    }
  } else {                           // theta/phi (q, ci): tile [q][136 ci]
    #pragma unroll
    for (int mf = 0; mf < 4; ++mf) {
      const int row = rb + mf * 16;  // ci
      f32x4 bv = *(const f32x4*)(bias + row);
      #pragma unroll
      for (int nf = 0; nf < 4; ++nf)
        #pragma unroll
        for (int r = 0; r < 4; ++r)
          tl[(cb + nf * 16) * 136 + row + r] = f2bf(acc[mf][nf][r] + bv[r]);
    }
    __syncthreads();
    u16* dst = (pt == 1 ? TH : PH) + (size_t)(v * 4 + b) * N_ * CI_;
    const int ci8 = (t & 15) * 8;
    #pragma unroll
    for (int rr = 0; rr < 8; ++rr) {
      const int q = (t >> 4) + rr * 16;
      *(u16x8*)(dst + (size_t)(col0 + q) * CI_ + ci8) =
          *(const u16x8*)(tl + q * 136 + ci8);
    }
  }
}

// ---------------- score epilogue helper (shared) ----------------
__device__ __forceinline__ void score_epi(char* lds, f32x4 (&acc)[4][4],
                                          u16* dst, int row0, int col0) {
  EPI_SETUP;
  const int t = (int)threadIdx.x;
  __syncthreads();
  u16* tl = (u16*)lds;
  #pragma unroll
  for (int mf = 0; mf < 4; ++mf)
    #pragma unroll
    for (int nf = 0; nf < 4; ++nf)
      #pragma unroll
      for (int r = 0; r < 4; ++r)
        tl[(rb + mf * 16 + r) * 136 + cb + nf * 16] = f2h(acc[mf][nf][r]);
  __syncthreads();
  const int k8 = (t & 15) * 8;
  #pragma unroll
  for (int rr = 0; rr < 8; ++rr) {
    const int q = (t >> 4) + rr * 16;
    *(u16x8*)(dst + (size_t)(row0 + q) * N_ + col0 + k8) =
        *(const u16x8*)(tl + q * 136 + k8);
  }
}

// ---------------- score (full-batch, 1-D grid 3888 XCD-swizzled) ------------
__global__ __launch_bounds__(256) void k_score_fb(const u16* TH, const u16* PH,
                                                  u16* F) {
  __shared__ char lds[49152];
  const int lid = xcd_swz();
  const int col0 = (lid % 18) * 128;        // k
  const int row0 = ((lid / 18) % 18) * 128; // q
  const int z = lid / 324;
  const int br = z % 3, b = z / 3;
  const char* Ab = (const char*)(TH + ((size_t)(br * 4 + b) * N_ + row0) * CI_);
  const char* Bb = (const char*)(PH + ((size_t)(br * 4 + b) * N_ + col0) * CI_);
  f32x4 acc[4][4] = {};
  gemm256c(Ab, 256, Bb, 256, 4, acc, lds);
  score_epi(lds, acc, F + (size_t)(b * 3 + br) * NN_, row0, col0);
}

// ---------------- score (per-batch fallback, grid (18,18,3)) ----------------
__global__ __launch_bounds__(256) void k_score(const u16* TH, const u16* PH,
                                               u16* F, int b) {
  __shared__ char lds[49152];
  const int col0 = blockIdx.x * 128;
  const int row0 = blockIdx.y * 128;
  const int br = blockIdx.z;
  const char* Ab = (const char*)(TH + ((size_t)(br * 4 + b) * N_ + row0) * CI_);
  const char* Bb = (const char*)(PH + ((size_t)(br * 4 + b) * N_ + col0) * CI_);
  f32x4 acc[4][4] = {};
  gemm256c(Ab, 256, Bb, 256, 4, acc, lds);
  score_epi(lds, acc, F + (size_t)br * NN_, row0, col0);
}

// ---------------- softsum core (shared) ----------------
__device__ __forceinline__ void softsum_row(const u16* F0, size_t brStride,
                                            u16* dst) {
  __shared__ float red[3][4];
  const int t = threadIdx.x;
  const bool ext = (t < 32);
  float e[3][16];
  float s0 = 0.f, s1 = 0.f, s2 = 0.f;
  #pragma unroll
  for (int i = 0; i < 3; ++i) {
    const u16* base = F0 + (size_t)i * brStride;
    u16x8 a = *(const u16x8*)(base + t * 8);
    #pragma unroll
    for (int jj = 0; jj < 8; ++jj) e[i][jj] = __expf(h2f(a.e[jj]));
    if (ext) {
      u16x8 c = *(const u16x8*)(base + 2048 + t * 8);
      #pragma unroll
      for (int jj = 0; jj < 8; ++jj) e[i][8 + jj] = __expf(h2f(c.e[jj]));
    } else {
      #pragma unroll
      for (int jj = 0; jj < 8; ++jj) e[i][8 + jj] = 0.f;
    }
    float ss = 0.f;
    #pragma unroll
    for (int s = 0; s < 16; ++s) ss += e[i][s];
    if (i == 0) s0 = ss; else if (i == 1) s1 = ss; else s2 = ss;
  }
  #pragma unroll
  for (int o = 32; o; o >>= 1) {
    s0 += __shfl_xor(s0, o);
    s1 += __shfl_xor(s1, o);
    s2 += __shfl_xor(s2, o);
  }
  const int w = t >> 6;
  __syncthreads();
  if ((t & 63) == 0) { red[0][w] = s0; red[1][w] = s1; red[2][w] = s2; }
  __syncthreads();
  const float inv0 = 1.f / (red[0][0] + red[0][1] + red[0][2] + red[0][3]);
  const float inv1 = 1.f / (red[1][0] + red[1][1] + red[1][2] + red[1][3]);
  const float inv2 = 1.f / (red[2][0] + red[2][1] + red[2][2] + red[2][3]);
  u16x8 o;
  #pragma unroll
  for (int jj = 0; jj < 8; ++jj)
    o.e[jj] = f2bf(e[0][jj] * inv0 + e[1][jj] * inv1 + e[2][jj] * inv2);
  *(u16x8*)(dst + t * 8) = o;
  if (ext) {
    #pragma unroll
    for (int jj = 0; jj < 8; ++jj)
      o.e[jj] = f2bf(e[0][8 + jj] * inv0 + e[1][8 + jj] * inv1 + e[2][8 + jj] * inv2);
    *(u16x8*)(dst + 2048 + t * 8) = o;
  }
}

__global__ __launch_bounds__(256) void k_softsum(const u16* F, u16* Abf, int b) {
  const int q = blockIdx.x;
  softsum_row(F + (size_t)q * N_, (size_t)NN_,
              Abf + ((size_t)b * N_ + q) * N_);
}

__global__ __launch_bounds__(256) void k_softsum_fb(const u16* F, u16* Abf) {
  const int b = blockIdx.x / N_, q = blockIdx.x % N_;
  softsum_row(F + (size_t)(b * 3) * NN_ + (size_t)q * N_, (size_t)NN_,
              Abf + ((size_t)b * N_ + q) * N_);
}

// ---------------- pv (256t, NO K-split, grid 216 XCD-swizzled, kIters=72) ---
__global__ __launch_bounds__(256) void k_pv(const u16* Abf, const u16* GP,
                                            u16* Y) {
  __shared__ char lds[49152];
  const int lid = xcd_swz();
  const int j = lid % 3;
  const int row0 = ((lid / 3) % 18) * 128; // q
  const int b = lid / 54;
  const char* Ab = (const char*)(Abf + ((size_t)b * N_ + row0) * N_);
  const char* Bb = (const char*)(GP + (size_t)(j * 4 + b) * CI_ * N_);
  f32x4 acc[4][4] = {};
  gemm256c(Ab, 4608, Bb, 4608, 72, acc, lds);
  EPI_SETUP;
  const int t = (int)threadIdx.x;
  u16* dst = Y + ((size_t)b * N_) * 384;
  u16* tl = (u16*)lds;
  const int jc4 = (t & 15) * 4;
  #pragma unroll
  for (int p = 0; p < 2; ++p) {
    __syncthreads();
    if ((ew & 1) == p) {
      #pragma unroll
      for (int mf = 0; mf < 4; ++mf)
        #pragma unroll
        for (int nf = 0; nf < 4; ++nf)
          #pragma unroll
          for (int r = 0; r < 4; ++r)
            tl[(rb + mf * 16 + r) * 72 + (el & 15) + nf * 16] =
                f2bf(acc[mf][nf][r]);
    }
    __syncthreads();
    #pragma unroll
    for (int rr = 0; rr < 8; ++rr) {
      const int q = (t >> 4) + rr * 16;
      *(u16x4*)(dst + (size_t)(row0 + q) * 384 + j * 128 + p * 64 + jc4) =
          *(const u16x4*)(tl + q * 72 + jc4);
    }
  }
}

// ---------------- zcat (256t, 1-D grid 432 XCD-swizzled, kIters=4) ----------
// Residual from XT (bf16, q-major, coalesced). Epilogue: phase-1
// tl[q][136c] = bf16(acc + wzb); phase-2 (v + xt)*dww + dwb on read-back.
struct ZA { const float* wzb[3]; const float* dww; const float* dwb; };
__global__ __launch_bounds__(256) void k_zcat(const u16* WZ, const u16* Y,
                                              const u16* XT, u16* DW, ZA za) {
  __shared__ char lds[49152];
  const int lid = xcd_swz();
  const int col0 = (lid % 18) * 128;        // q
  const int row0 = ((lid / 18) % 2) * 128;  // c within 256
  const int z = lid / 36;
  const int j = z % 3, b = z / 3;
  const char* Ab = (const char*)(WZ + (size_t)j * 32768 + (size_t)row0 * CI_);
  const char* Bb = (const char*)(Y + ((size_t)b * N_ + col0) * 384 + j * CI_);
  f32x4 acc[4][4] = {};
  gemm256c(Ab, 256, Bb, 768, 4, acc, lds);
  EPI_SETUP;
  const int t = (int)threadIdx.x;
  u16* tl = (u16*)lds;
  __syncthreads();
  #pragma unroll
  for (int mf = 0; mf < 4; ++mf) {
    const int cl = row0 + rb + mf * 16;              // 0..255
    f32x4 wb = *(const f32x4*)(za.wzb[j] + cl);
    #pragma unroll
    for (int nf = 0; nf < 4; ++nf)
      #pragma unroll
      for (int r = 0; r < 4; ++r)
        tl[(cb + nf * 16) * 136 + rb + mf * 16 + r] =
            f2bf(acc[mf][nf][r] + wb[r]);
  }
  __syncthreads();
  const u16* xt = XT + ((size_t)(j * 4 + b) * N_ + col0) * 256 + row0;
  const int c8 = (t & 15) * 8;
  const int cg0 = j * 256 + row0 + c8;
  f32x4 sc0 = *(const f32x4*)(za.dww + cg0);
  f32x4 sc1 = *(const f32x4*)(za.dww + cg0 + 4);
  f32x4 sb0 = *(const f32x4*)(za.dwb + cg0);
  f32x4 sb1 = *(const f32x4*)(za.dwb + cg0 + 4);
  #pragma unroll
  for (int rr = 0; rr < 8; ++rr) {
    const int q = (t >> 4) + rr * 16;
    u16x8 v  = *(const u16x8*)(tl + q * 136 + c8);
    u16x8 xr = *(const u16x8*)(xt + (size_t)q * 256 + c8);
    u16x8 o;
    #pragma unroll
    for (int jj = 0; jj < 4; ++jj) {
      o.e[jj]     = f2bf((bf2f(v.e[jj])     + bf2f(xr.e[jj]))     * sc0[jj] + sb0[jj]);
      o.e[jj + 4] = f2bf((bf2f(v.e[jj + 4]) + bf2f(xr.e[jj + 4])) * sc1[jj] + sb1[jj]);
    }
    *(u16x8*)(DW + ((size_t)b * N_ + col0 + q) * 768 + j * 256 + row0 + c8) = o;
  }
}

// ---------------- final (256t, grid 576 swizzled, kIters=24) -----------------
__global__ __launch_bounds__(256) void k_final(const u16* PWb, const u16* DW,
                                               const float* pwb, const float* xin,
                                               const float* pp, float* out) {
  __shared__ char lds[49152];
  const int lid = xcd_swz();
  const int row0 = (lid % 18) * 128;        // q strip
  const int col0 = ((lid / 18) % 8) * 128;  // o strip
  const int b = lid / 144;
  const char* Ab = (const char*)(DW + ((size_t)b * N_ + row0) * 768);
  const char* Bb = (const char*)(PWb + (size_t)col0 * 768);
  EPI_SETUP;
  const int t = (int)threadIdx.x;
  const float pscale = pp[0];
  const int q4 = (t & 31) * 4;
  const int ob = (t >> 5) * 8;
  f32x4 xv[2][8];
  #pragma unroll
  for (int p = 0; p < 2; ++p)
    #pragma unroll
    for (int rr = 0; rr < 8; ++rr)
      xv[p][rr] = *(const f32x4*)(
          xin + ((size_t)b * 1024 + col0 + p * 64 + ob + rr) * N_ + row0 + q4);
  f32x4 acc[4][4] = {};
  gemm256c(Ab, 1536, Bb, 1536, 24, acc, lds);
  float* tl = (float*)lds;
  #pragma unroll
  for (int p = 0; p < 2; ++p) {
    __syncthreads();
    if ((ew & 1) == p) {                   // this wave-column owns o-half p
      #pragma unroll
      for (int mf = 0; mf < 4; ++mf)
        #pragma unroll
        for (int nf = 0; nf < 4; ++nf)
          #pragma unroll
          for (int r = 0; r < 4; ++r)
            tl[((el & 15) + nf * 16) * 132 + rb + mf * 16 + r] = acc[mf][nf][r];
    }
    __syncthreads();
    #pragma unroll
    for (int rr = 0; rr < 8; ++rr) {
      const int og = col0 + p * 64 + ob + rr;
      const float bb = pwb[og];
      f32x4 a4 = *(const f32x4*)(tl + (ob + rr) * 132 + q4);
      f32x4 o4;
      #pragma unroll
      for (int r = 0; r < 4; ++r)
        o4[r] = xv[p][rr][r] + pscale * (a4[r] + bb);
      *(f32x4*)(out + ((size_t)b * 1024 + og) * N_ + row0 + q4) = o4;
    }
  }
}

// ---------------------------------------------------------------------------
extern "C" void kernel_launch(void* const* d_in, const int* in_sizes, int n_in,
                              void* d_out, int out_size, void* d_ws, size_t ws_size,
                              hipStream_t stream) {
  const float* x0  = (const float*)d_in[0];
  const float* x1  = (const float*)d_in[1];
  const float* x2  = (const float*)d_in[2];
  const float* xin = (const float*)d_in[3];
  const float* g_w = (const float*)d_in[4];
  const float* g_b = (const float*)d_in[5];
  const float* thw[3] = {(const float*)d_in[6],  (const float*)d_in[10], (const float*)d_in[14]};
  const float* thb[3] = {(const float*)d_in[7],  (const float*)d_in[11], (const float*)d_in[15]};
  const float* phw[3] = {(const float*)d_in[8],  (const float*)d_in[12], (const float*)d_in[16]};
  const float* phb[3] = {(const float*)d_in[9],  (const float*)d_in[13], (const float*)d_in[17]};
  const float* Wm[3]  = {(const float*)d_in[18], (const float*)d_in[20], (const float*)d_in[22]};
  const float* Wmb[3] = {(const float*)d_in[19], (const float*)d_in[21], (const float*)d_in[23]};
  const float* dww = (const float*)d_in[24];
  const float* dwb = (const float*)d_in[25];
  const float* pww = (const float*)d_in[26];
  const float* pwb = (const float*)d_in[27];
  const float* pp  = (const float*)d_in[28];

  char* wsb = (char*)d_ws;
  u16*   WB  = (u16*)(wsb + B_WB);
  u16*   WZ  = (u16*)(wsb + B_WZ);
  u16*   PW  = (u16*)(wsb + B_PW);
  u16*   XT  = (u16*)(wsb + B_R1);   // stays ALIVE through zcat
  u16*   TH  = (u16*)(wsb + B_R2);
  u16*   PH  = TH + (size_t)3 * B_ * N_ * CI_;
  u16*   DW  = (u16*)(wsb + B_R2);   // overlays TH/PH (dead after last score)
  u16*   GP  = (u16*)(wsb + B_GP);
  u16*   Y   = (u16*)(wsb + B_F);    // exact 7,077,888-byte fit; F dead there

  const bool full = (ws_size >= WS_FULL);
  u16* Fh  = full ? (u16*)(wsb + B_FF) : (u16*)(wsb + B_F);
  u16* Abf = full ? (u16*)(wsb + B_AF) : (u16*)(wsb + B_A);
  // fallback: Y at B_F overlays Fh only AFTER all softsums (Fh dead). ✓

  CvtA ca;
  ca.s[0] = g_w; ca.s[1] = thw[0]; ca.s[2] = phw[0];
  ca.s[3] = g_w; ca.s[4] = thw[1]; ca.s[5] = phw[1];
  ca.s[6] = g_w; ca.s[7] = thw[2]; ca.s[8] = phw[2];
  ca.s[9] = Wm[0]; ca.s[10] = Wm[1]; ca.s[11] = Wm[2];
  ca.s[12] = pww;
  ca.x[0] = x0; ca.x[1] = x1; ca.x[2] = x2;

  ProjA pa;
  pa.bias[0] = g_b; pa.bias[1] = thb[0]; pa.bias[2] = phb[0];
  pa.bias[3] = g_b; pa.bias[4] = thb[1]; pa.bias[5] = phb[1];
  pa.bias[6] = g_b; pa.bias[7] = thb[2]; pa.bias[8] = phb[2];

  ZA za;
  za.wzb[0] = Wmb[0]; za.wzb[1] = Wmb[1]; za.wzb[2] = Wmb[2];
  za.dww = dww; za.dwb = dwb;

  k_cvt<<<dim3(36, 4, 13), 256, 0, stream>>>(ca, WB, XT);
  k_proj<<<dim3(648), 256, 0, stream>>>(WB, XT, TH, PH, GP, pa);
  if (full) {
    k_score_fb  <<<dim3(3888),   256, 0, stream>>>(TH, PH, Fh);
    k_softsum_fb<<<dim3(4 * N_), 256, 0, stream>>>(Fh, Abf);
  } else {
    for (int b = 0; b < B_; ++b) {
      k_score  <<<dim3(18, 18, 3), 256, 0, stream>>>(TH, PH, Fh, b);
      k_softsum<<<dim3(N_),        256, 0, stream>>>(Fh, Abf, b);
    }
  }
  k_pv   <<<dim3(216), 256, 0, stream>>>(Abf, GP, Y);
  k_zcat <<<dim3(432), 256, 0, stream>>>(WZ, Y, XT, DW, za);
  k_final<<<dim3(576), 256, 0, stream>>>(PW, DW, pwb, xin, pp, (float*)d_out);
}